// Round 14
// baseline (48.460 us; speedup 1.0000x reference)
//
#include <hip/hip_runtime.h>

// BahdanauAttnDecoderRNN single-step decode, MI355X — 4 stream-ordered kernels.
// Reference dead code: softmax over size-1 axis => attn_weights == 1.0;
// attn_W/attn_b/scores dead; attn_applied = colsum(encoder_outputs).
// Live work ~178 MB f32 reads (Wout 131 MB dominant) => ~28 us HBM roofline.
// Measured lessons (13 rounds):
//   - NO intra-kernel polling / grid.sync (R4 441us, R5 486us, R8 420us+wrong).
//   - NO serial winner-reduce on critical path (R10 +24us).
//   - NO extra dispatch nodes (memset node alone ~ +11us, R11).
//   - Logits stream: 1000 blocks x 32 rows (8/wave) is the sweet spot.
//   - R13 NaN: (1-e)/(1+e) tanh overflows for |x|>44 — gate inputs reach
//     +-100 here (colsum sigma~45 => gi2 sigma~29). Use |x|-based forms.
//   D1: colsum partials (64 chunks) + gh + emb-half gi (384 blks, 2 rows/wave)
//       + attn ones
//   D2: per-block redundant partial-reduce + gi2 (192 x 16 rows)
//   D3: robust-fast gates redundant per block + 32-row logits (8/wave) + (m,s)
//   D4: fixed-order reduce of 1000 partials + in-place log-softmax

namespace {
constexpr int H = 1024;
constexpr int V = 32000;
constexpr int S = 2048;
constexpr int NTHR = 256;
constexpr int CS_BLKS = 64;             // colsum chunks (128 KB each)
constexpr int CS_ROWS = S / CS_BLKS;    // 32 rows per chunk
constexpr int GRU_BLKS = 384;           // 3072 rows / 8 per block (2 per wave)
constexpr int D1_BLKS = CS_BLKS + GRU_BLKS + 1;  // 449
constexpr int D2_BLKS = 192;            // 16 gi2 rows each
constexpr int D3_BLKS = 1000;           // 32 logits rows each (8 per wave)
constexpr int RPW = 8;                  // rows per wave in D3
constexpr int D4_BLKS = V / NTHR;       // 125
}

__device__ __forceinline__ float wave_sum(float v) {
#pragma unroll
    for (int off = 32; off > 0; off >>= 1) v += __shfl_xor(v, off, 64);
    return v;
}
__device__ __forceinline__ float wave_max(float v) {
#pragma unroll
    for (int off = 32; off > 0; off >>= 1) v = fmaxf(v, __shfl_xor(v, off, 64));
    return v;
}
__device__ __forceinline__ float dot4(float4 a, float4 b) {
    return a.x * b.x + a.y * b.y + a.z * b.z + a.w * b.w;
}
// Overflow-safe fast sigmoid/tanh on v_exp_f32: exponent argument is always
// <= 0, so __expf never overflows; e in (0,1]. Error ~1e-6 (threshold 2.6e-1).
__device__ __forceinline__ float fsigmoid(float x) {
    const float e = __expf(-fabsf(x));        // (0,1]
    const float p = 1.f / (1.f + e);          // sigmoid(|x|)
    return x >= 0.f ? p : 1.f - p;
}
__device__ __forceinline__ float ftanh(float x) {
    const float e = __expf(-2.f * fabsf(x));  // (0,1]
    const float p = (1.f - e) / (1.f + e);    // tanh(|x|)
    return x >= 0.f ? p : -p;
}

// D1: colsum partials + gh & emb-half of gi (2 rows/wave) + attn ones.
__global__ __launch_bounds__(NTHR) void k_front(
    const float* __restrict__ enc, const float* __restrict__ Whh,
    const float* __restrict__ Wih, const float* __restrict__ bih,
    const float* __restrict__ bhh, const float* __restrict__ hin,
    const float* __restrict__ emb, const int* __restrict__ word,
    float* __restrict__ part, float* __restrict__ gi, float* __restrict__ gh,
    float* __restrict__ out) {
    const int b = blockIdx.x, t = threadIdx.x;
    if (b < CS_BLKS) {
        // rows [b*32, b*32+32); thread t owns float4-column t
        const float4* e = (const float4*)enc + (size_t)b * CS_ROWS * (H / 4) + t;
        float4 acc = make_float4(0.f, 0.f, 0.f, 0.f);
#pragma unroll
        for (int r = 0; r < CS_ROWS; ++r) {
            float4 v = e[(size_t)r * (H / 4)];
            acc.x += v.x; acc.y += v.y; acc.z += v.z; acc.w += v.w;
        }
        ((float4*)part)[b * (H / 4) + t] = acc;
    } else if (b < CS_BLKS + GRU_BLKS) {
        const int lane = t & 63, w = t >> 6;
        const int row0 = (b - CS_BLKS) * 8 + w * 2;  // 2 rows per wave, < 3072
        const float4* wh0 = (const float4*)Whh + (size_t)(row0 + 0) * (H / 4);
        const float4* wh1 = (const float4*)Whh + (size_t)(row0 + 1) * (H / 4);
        const float4* wi0 = (const float4*)Wih + (size_t)(row0 + 0) * (2 * H / 4);
        const float4* wi1 = (const float4*)Wih + (size_t)(row0 + 1) * (2 * H / 4);
        const float4* xh = (const float4*)hin;
        const float4* er = (const float4*)emb + (size_t)word[0] * (H / 4);
        float ah0 = 0.f, ah1 = 0.f, ai0 = 0.f, ai1 = 0.f;
#pragma unroll
        for (int it = 0; it < 4; ++it) {
            const int idx = it * 64 + lane;
            const float4 x4 = xh[idx];
            float4 e4 = er[idx];
            e4.x = fmaxf(e4.x, 0.f); e4.y = fmaxf(e4.y, 0.f);
            e4.z = fmaxf(e4.z, 0.f); e4.w = fmaxf(e4.w, 0.f);
            ah0 += dot4(wh0[idx], x4);
            ah1 += dot4(wh1[idx], x4);
            ai0 += dot4(wi0[idx], e4);
            ai1 += dot4(wi1[idx], e4);
        }
        ah0 = wave_sum(ah0);
        ah1 = wave_sum(ah1);
        ai0 = wave_sum(ai0);
        ai1 = wave_sum(ai1);
        if (lane == 0) {
            gh[row0 + 0] = ah0 + bhh[row0 + 0];
            gh[row0 + 1] = ah1 + bhh[row0 + 1];
            gi[row0 + 0] = ai0 + bih[row0 + 0];  // colsum half lives in gi2
            gi[row0 + 1] = ai1 + bih[row0 + 1];
        }
    } else {
        // attn_weights are exactly 1.0 (softmax over size-1 axis)
#pragma unroll
        for (int k = 0; k < S / NTHR; ++k) out[V + H + k * NTHR + t] = 1.0f;
    }
}

// D2: per-block redundant reduce of 64 colsum partials -> relu -> LDS;
// then 16 rows of gi2 = Wih[:, H:2H] . rn.
__global__ __launch_bounds__(NTHR) void k_gi2(
    const float* __restrict__ Wih, const float* __restrict__ part,
    float* __restrict__ gi2) {
    __shared__ float4 rn[H / 4];
    const int t = threadIdx.x, lane = t & 63, w = t >> 6;
    float4 acc = make_float4(0.f, 0.f, 0.f, 0.f);
#pragma unroll 8
    for (int c = 0; c < CS_BLKS; ++c) {
        float4 v = ((const float4*)part)[c * (H / 4) + t];
        acc.x += v.x; acc.y += v.y; acc.z += v.z; acc.w += v.w;
    }
    acc.x = fmaxf(acc.x, 0.f); acc.y = fmaxf(acc.y, 0.f);
    acc.z = fmaxf(acc.z, 0.f); acc.w = fmaxf(acc.w, 0.f);
    rn[t] = acc;
    __syncthreads();
#pragma unroll
    for (int i = 0; i < 4; ++i) {
        const int row = blockIdx.x * 16 + w * 4 + i;  // < 3072
        const float4* wr = (const float4*)Wih + (size_t)row * (2 * H / 4) + (H / 4);
        float a = 0.f;
#pragma unroll
        for (int it = 0; it < 4; ++it) {
            const int idx = it * 64 + lane;
            a += dot4(wr[idx], rn[idx]);
        }
        a = wave_sum(a);
        if (lane == 0) gi2[row] = a;
    }
}

// D3: robust-fast gates redundant per block -> h_new in LDS -> 32-row Wout
// matvec (8 rows/wave, register batch) -> raw logits + per-block (m,s).
__global__ __launch_bounds__(NTHR) void k_logits(
    const float* __restrict__ gi, const float* __restrict__ gi2,
    const float* __restrict__ gh, const float* __restrict__ hin,
    const float* __restrict__ Wout, const float* __restrict__ bout,
    float* __restrict__ out, float* __restrict__ partm, float* __restrict__ parts) {
    __shared__ float hnew[H];
    __shared__ float bm[4], bs[4];
    const int t = threadIdx.x, lane = t & 63, w = t >> 6;
#pragma unroll
    for (int q = 0; q < 4; ++q) {
        const int j = q * NTHR + t;
        const float r = fsigmoid(gi[j] + gi2[j] + gh[j]);
        const float z = fsigmoid(gi[H + j] + gi2[H + j] + gh[H + j]);
        const float n = ftanh(gi[2 * H + j] + gi2[2 * H + j] + r * gh[2 * H + j]);
        const float hv = (1.f - z) * n + z * hin[j];
        hnew[j] = hv;
        if (blockIdx.x == 0) out[V + j] = hv;  // hidden-state output
    }
    __syncthreads();
    const float4* hn4 = (const float4*)hnew;
    const float4 x0 = hn4[lane], x1 = hn4[64 + lane];
    const float4 x2 = hn4[128 + lane], x3 = hn4[192 + lane];
    float a[RPW];
#pragma unroll 2
    for (int i = 0; i < RPW; ++i) {
        const int row = blockIdx.x * 32 + w * RPW + i;  // < 32000
        const float4* wr = (const float4*)Wout + (size_t)row * (H / 4);
        float v = dot4(wr[lane], x0) + dot4(wr[64 + lane], x1) +
                  dot4(wr[128 + lane], x2) + dot4(wr[192 + lane], x3);
        a[i] = wave_sum(v) + bout[row];  // identical on all lanes
        if (lane == 0) out[row] = a[i];  // raw logit
    }
    float m = a[0];
#pragma unroll
    for (int i = 1; i < RPW; ++i) m = fmaxf(m, a[i]);
    float s = 0.f;
#pragma unroll
    for (int i = 0; i < RPW; ++i) s += __expf(a[i] - m);  // arg <= 0: safe
    if (lane == 0) { bm[w] = m; bs[w] = s; }
    __syncthreads();
    if (t == 0) {
        const float M = fmaxf(fmaxf(bm[0], bm[1]), fmaxf(bm[2], bm[3]));
        const float ss = bs[0] * __expf(bm[0] - M) + bs[1] * __expf(bm[1] - M) +
                         bs[2] * __expf(bm[2] - M) + bs[3] * __expf(bm[3] - M);
        partm[blockIdx.x] = M;
        parts[blockIdx.x] = ss;
    }
}

// D4: redundant fixed-order reduce of 1000 partials + in-place log-softmax.
__global__ __launch_bounds__(NTHR) void k_final(
    const float* __restrict__ partm, const float* __restrict__ parts,
    float* __restrict__ out) {
    __shared__ float ms[4], ss[4];
    const int t = threadIdx.x, lane = t & 63, w = t >> 6;
    float m = -3.4e38f;
    for (int k = t; k < D3_BLKS; k += NTHR) m = fmaxf(m, partm[k]);
    m = wave_max(m);
    if (lane == 0) ms[w] = m;
    __syncthreads();
    const float M = fmaxf(fmaxf(ms[0], ms[1]), fmaxf(ms[2], ms[3]));
    float s = 0.f;
    for (int k = t; k < D3_BLKS; k += NTHR) s += parts[k] * expf(partm[k] - M);
    s = wave_sum(s);
    if (lane == 0) ss[w] = s;
    __syncthreads();
    const float L = logf(ss[0] + ss[1] + ss[2] + ss[3]);
    const int g = blockIdx.x * NTHR + t;  // 125*256 = 32000
    out[g] = out[g] - M - L;
}

extern "C" void kernel_launch(void* const* d_in, const int* in_sizes, int n_in,
                              void* d_out, int out_size, void* d_ws, size_t ws_size,
                              hipStream_t stream) {
    const int*   word = (const int*)d_in[0];
    const float* hin  = (const float*)d_in[1];
    const float* enc  = (const float*)d_in[2];
    const float* emb  = (const float*)d_in[3];
    // d_in[4] attn_W, d_in[5] attn_b: dead (softmax over size-1 axis)
    const float* Wih  = (const float*)d_in[6];
    const float* Whh  = (const float*)d_in[7];
    const float* bih  = (const float*)d_in[8];
    const float* bhh  = (const float*)d_in[9];
    const float* Wout = (const float*)d_in[10];
    const float* bout = (const float*)d_in[11];
    float* out = (float*)d_out;
    float* ws  = (float*)d_ws;

    float* part  = ws;                  // [64*1024]
    float* gi    = part + CS_BLKS * H;  // [3072]
    float* gi2   = gi + 3 * H;          // [3072]
    float* gh    = gi2 + 3 * H;         // [3072]
    float* partm = gh + 3 * H;          // [1000]
    float* parts = partm + D3_BLKS;     // [1000]

    k_front<<<D1_BLKS, NTHR, 0, stream>>>(enc, Whh, Wih, bih, bhh, hin, emb, word,
                                          part, gi, gh, out);
    k_gi2<<<D2_BLKS, NTHR, 0, stream>>>(Wih, part, gi2);
    k_logits<<<D3_BLKS, NTHR, 0, stream>>>(gi, gi2, gh, hin, Wout, bout, out,
                                           partm, parts);
    k_final<<<D4_BLKS, NTHR, 0, stream>>>(partm, parts, out);
}